// Round 2
// baseline (191.698 us; speedup 1.0000x reference)
//
#include <hip/hip_runtime.h>
#include <hip/hip_bf16.h>

#define N_NODES 8192
#define DIM 128
#define MASK_THRESH 0.8f
#define RG (N_NODES / 16)   // 512 row-groups

using f32x4  = __attribute__((ext_vector_type(4))) float;
using bf16x8 = __attribute__((ext_vector_type(8))) short;

static __device__ __forceinline__ short f2bf(float f) {
    unsigned u = __builtin_bit_cast(unsigned, f);
    u += 0x7fffu + ((u >> 16) & 1u);
    return (short)(u >> 16);
}

// ---------------------------------------------------------------------------
// Kernel 1: Vt[d][j] = dot(X[j,:], W[d,:]) + b[d], bf16, Vt is [128][8192]
// ---------------------------------------------------------------------------
__global__ __launch_bounds__(256) void build_vt_kernel(
    const float* __restrict__ X, const float* __restrict__ W,
    const float* __restrict__ bias, short* __restrict__ Vt) {
    __shared__ float xs[32][128];
    const int jt = blockIdx.x * 32;
    for (int e = threadIdx.x; e < 32 * 128; e += 256) {
        xs[e >> 7][e & 127] = X[(size_t)(jt + (e >> 7)) * DIM + (e & 127)];
    }
    __syncthreads();
    const int d  = threadIdx.x & 127;
    const int jh = threadIdx.x >> 7;
    float bv = bias[d];
    float acc[16];
#pragma unroll
    for (int i = 0; i < 16; i++) acc[i] = bv;
    const float* wrow = W + (size_t)d * DIM;
    for (int k = 0; k < DIM; k += 4) {
        f32x4 wv = *(const f32x4*)(wrow + k);
#pragma unroll
        for (int i = 0; i < 16; i++) {
            f32x4 xv = *(const f32x4*)(&xs[jh * 16 + i][k]);
            acc[i] += xv[0] * wv[0] + xv[1] * wv[1] + xv[2] * wv[2] + xv[3] * wv[3];
        }
    }
    bf16x8 o0, o1;
#pragma unroll
    for (int i = 0; i < 8; i++) { o0[i] = f2bf(acc[i]); o1[i] = f2bf(acc[8 + i]); }
    short* dst = Vt + (size_t)d * N_NODES + jt + jh * 16;
    *(bf16x8*)(dst)     = o0;
    *(bf16x8*)(dst + 8) = o1;
}

// ---------------------------------------------------------------------------
// Kernel 2: fused masked-softmax(A) @ V over a K-chunk.
//   grid = RG * S blocks; block (rg, chunk) covers rows rg*16..+16,
//   k in [chunk*kchunk, +kchunk). 8 waves split the chunk 8 ways.
//   WRITE_PARTIAL=1: store numerator tile + Z to workspace.
//   WRITE_PARTIAL=0: finalize in-kernel (fallback, S==1).
// ---------------------------------------------------------------------------
template <int WRITE_PARTIAL>
__global__ __launch_bounds__(512, 4) void fused_softmax_pv_kernel(
    const float* __restrict__ A, const short* __restrict__ Vt,
    float* __restrict__ dst, float* __restrict__ Zp, int kchunk) {
    __shared__ float accs[4][16][132];
    __shared__ float zs[8][16];

    const int tid   = threadIdx.x;
    const int wid   = tid >> 6;
    const int lane  = tid & 63;
    const int row_a = lane & 15;
    const int kg    = lane >> 4;
    const int rg    = blockIdx.x & (RG - 1);
    const int chunk = blockIdx.x >> 9;
    const int r0    = rg * 16;
    const int klen  = kchunk >> 3;                 // per-wave k extent
    const int k0    = chunk * kchunk + wid * klen;

    f32x4 acc[8];
#pragma unroll
    for (int t = 0; t < 8; t++) acc[t] = (f32x4)0.0f;
    float zacc = 0.0f;

    const float* aptr  = A  + (size_t)(r0 + row_a) * N_NODES + k0 + kg * 8;
    const short* bbase = Vt + (size_t)row_a * N_NODES + k0 + kg * 8;

    // prologue: first A octet in flight
    f32x4 ca0 = *(const f32x4*)(aptr);
    f32x4 ca1 = *(const f32x4*)(aptr + 4);

    for (int ks = 0; ks < klen; ks += 32) {
        // independent Vt loads for this iteration (8 in flight)
        bf16x8 bfv[8];
#pragma unroll
        for (int t = 0; t < 8; t++)
            bfv[t] = *(const bf16x8*)(bbase + (size_t)t * 16 * N_NODES + ks);
        // prefetch next A octet
        f32x4 na0, na1;
        if (ks + 32 < klen) {
            na0 = *(const f32x4*)(aptr + ks + 32);
            na1 = *(const f32x4*)(aptr + ks + 36);
        }
        float p[8];
#pragma unroll
        for (int i = 0; i < 4; i++) {
            p[i]     = (ca0[i] > MASK_THRESH) ? __expf(ca0[i]) : 0.0f;
            p[i + 4] = (ca1[i] > MASK_THRESH) ? __expf(ca1[i]) : 0.0f;
        }
        bf16x8 af;
#pragma unroll
        for (int i = 0; i < 8; i++) { zacc += p[i]; af[i] = f2bf(p[i]); }
#pragma unroll
        for (int t = 0; t < 8; t++)
            acc[t] = __builtin_amdgcn_mfma_f32_16x16x32_bf16(af, bfv[t], acc[t], 0, 0, 0);
        ca0 = na0;
        ca1 = na1;
    }

    // Z: fold the 4 k-groups; lane==row for lane<16
    zacc += __shfl_xor(zacc, 16);
    zacc += __shfl_xor(zacc, 32);
    if (lane < 16) zs[wid][lane] = zacc;

    if (wid < 4) {
#pragma unroll
        for (int t = 0; t < 8; t++)
#pragma unroll
            for (int r = 0; r < 4; r++)
                accs[wid][kg * 4 + r][t * 16 + row_a] = acc[t][r];
    }
    __syncthreads();
    if (wid >= 4) {
#pragma unroll
        for (int t = 0; t < 8; t++)
#pragma unroll
            for (int r = 0; r < 4; r++)
                accs[wid - 4][kg * 4 + r][t * 16 + row_a] += acc[t][r];
    }
    __syncthreads();

    if (WRITE_PARTIAL) {
        float* nd = dst + (size_t)blockIdx.x * (16 * 128);
        for (int e = tid; e < 16 * 128; e += 512) {
            const int row = e >> 7;
            const int col = e & 127;
            float s = 0.0f;
#pragma unroll
            for (int w = 0; w < 4; w++) s += accs[w][row][col];
            nd[e] = s;
        }
        if (tid < 16) {
            float z = 0.0f;
#pragma unroll
            for (int w = 0; w < 8; w++) z += zs[w][tid];
            Zp[(size_t)blockIdx.x * 16 + tid] = z;
        }
    } else {
        for (int e = tid; e < 16 * 128; e += 512) {
            const int row = e >> 7;
            const int col = e & 127;
            float s = 0.0f, zt = 0.0f;
#pragma unroll
            for (int w = 0; w < 4; w++) s += accs[w][row][col];
#pragma unroll
            for (int w = 0; w < 8; w++) zt += zs[w][row];
            float v = s / zt;
            dst[(size_t)(r0 + row) * DIM + col] = (v > 0.0f) ? v : 0.01f * v;
        }
    }
}

// ---------------------------------------------------------------------------
// Kernel 3: sum S partials, normalize, leaky_relu.
// ---------------------------------------------------------------------------
__global__ __launch_bounds__(256) void reduce_kernel(
    const float* __restrict__ num, const float* __restrict__ Zp,
    float* __restrict__ out, int S) {
    const int idx = blockIdx.x * 256 + threadIdx.x;   // flat over N*DIM
    const int r  = idx >> 7;
    const int c  = idx & 127;
    const int rg = r >> 4;
    const int rr = r & 15;
    float s = 0.0f, z = 0.0f;
    for (int p = 0; p < S; p++) {
        s += num[((size_t)(p * RG + rg)) * 2048 + rr * 128 + c];
        z += Zp[(size_t)(p * RG + rg) * 16 + rr];
    }
    float v = s / z;
    out[idx] = (v > 0.0f) ? v : 0.01f * v;
}

extern "C" void kernel_launch(void* const* d_in, const int* in_sizes, int n_in,
                              void* d_out, int out_size, void* d_ws, size_t ws_size,
                              hipStream_t stream) {
    const float* A = (const float*)d_in[0];
    const float* X = (const float*)d_in[1];
    const float* W = (const float*)d_in[2];
    const float* b = (const float*)d_in[3];
    float* out = (float*)d_out;

    const size_t VT_BYTES = (size_t)DIM * N_NODES * 2;      // 2 MiB bf16
    short* Vt = (short*)d_ws;
    build_vt_kernel<<<N_NODES / 32, 256, 0, stream>>>(X, W, b, Vt);

    // pick largest split S whose partials fit the workspace
    const size_t per_split = ((size_t)RG * 16 * 128 + (size_t)RG * 16) * sizeof(float);
    int S = 0;
    for (int cand = 4; cand >= 1; cand >>= 1) {
        if (VT_BYTES + (size_t)cand * per_split <= ws_size) { S = cand; break; }
    }

    if (S >= 2) {
        float* num = (float*)((char*)d_ws + VT_BYTES);
        float* Zp  = num + (size_t)S * RG * 16 * 128;
        fused_softmax_pv_kernel<1><<<RG * S, 512, 0, stream>>>(A, Vt, num, Zp, N_NODES / S);
        reduce_kernel<<<(N_NODES * DIM) / 256, 256, 0, stream>>>(num, Zp, out, S);
    } else {
        fused_softmax_pv_kernel<0><<<RG, 512, 0, stream>>>(A, Vt, out, nullptr, N_NODES);
    }
}

// Round 3
// 102.871 us; speedup vs baseline: 1.8635x; 1.8635x over previous
//
#include <hip/hip_runtime.h>
#include <hip/hip_bf16.h>

#define N_NODES 8192
#define DIM 128
#define MASK_THRESH 0.8f
#define RB 256            // row-blocks: 8192 / 32 rows
#define KSTEP 128         // k elements staged per step

using f32x4  = __attribute__((ext_vector_type(4))) float;
using bf16x8 = __attribute__((ext_vector_type(8))) short;

static __device__ __forceinline__ short f2bf(float f) {
    unsigned u = __builtin_bit_cast(unsigned, f);
    u += 0x7fffu + ((u >> 16) & 1u);
    return (short)(u >> 16);
}

// async global->LDS, 16B per lane; LDS dest wave-uniform base + lane*16 (linear)
static __device__ __forceinline__ void gload16(const void* gsrc, void* ldst) {
    __builtin_amdgcn_global_load_lds(
        (const __attribute__((address_space(1))) unsigned int*)gsrc,
        (__attribute__((address_space(3))) unsigned int*)ldst,
        16, 0, 0);
}

// ---------------------------------------------------------------------------
// Kernel 1: Vt[d][j] = dot(X[j,:], W[d,:]) + b[d], bf16, Vt is [128][8192]
// ---------------------------------------------------------------------------
__global__ __launch_bounds__(256) void build_vt_kernel(
    const float* __restrict__ X, const float* __restrict__ W,
    const float* __restrict__ bias, short* __restrict__ Vt) {
    __shared__ float xs[32][128];
    const int jt = blockIdx.x * 32;
    for (int e = threadIdx.x; e < 32 * 128; e += 256) {
        xs[e >> 7][e & 127] = X[(size_t)(jt + (e >> 7)) * DIM + (e & 127)];
    }
    __syncthreads();
    const int d  = threadIdx.x & 127;
    const int jh = threadIdx.x >> 7;
    float bv = bias[d];
    float acc[16];
#pragma unroll
    for (int i = 0; i < 16; i++) acc[i] = bv;
    const float* wrow = W + (size_t)d * DIM;
    for (int k = 0; k < DIM; k += 4) {
        f32x4 wv = *(const f32x4*)(wrow + k);
#pragma unroll
        for (int i = 0; i < 16; i++) {
            f32x4 xv = *(const f32x4*)(&xs[jh * 16 + i][k]);
            acc[i] += xv[0] * wv[0] + xv[1] * wv[1] + xv[2] * wv[2] + xv[3] * wv[3];
        }
    }
    bf16x8 o0, o1;
#pragma unroll
    for (int i = 0; i < 8; i++) { o0[i] = f2bf(acc[i]); o1[i] = f2bf(acc[8 + i]); }
    short* dst = Vt + (size_t)d * N_NODES + jt + jh * 16;
    *(bf16x8*)(dst)     = o0;
    *(bf16x8*)(dst + 8) = o1;
}

// ---------------------------------------------------------------------------
// Kernel 2: LDS-staged fused masked-softmax(A) @ V.
//   Block: 32 rows x kchunk. 8 waves = 2 rowgroups x 4 k-slices.
//   Per KSTEP=128: stage Vt[128][128] bf16 + A[32][128] f32 via global_load_lds
//   (pre-swizzled per-lane SOURCE addrs, linear LDS dest); compute waves read
//   swizzled ds_read_b128 fragments, exp+pack in-register, 8 MFMA per wave.
//   XOR swizzle: 16B-chunk index ^= (row & 7)  (both sides consistently).
// ---------------------------------------------------------------------------
template <int WRITE_PARTIAL>
__global__ __launch_bounds__(512, 4) void fused_kernel(
    const float* __restrict__ A, const short* __restrict__ Vt,
    float* __restrict__ dst, float* __restrict__ Zp, int kchunk) {

    __shared__ __align__(16) char smem[49152];   // Vt tile 32K + A tile 16K (reused as accs)
    __shared__ float zs[8][16];

    short* vt_s = (short*)smem;              // [128][128] bf16
    float* a_s  = (float*)(smem + 32768);    // [32][128] f32

    const int tid   = threadIdx.x;
    const int wid   = tid >> 6;
    const int lane  = tid & 63;
    const int row_a = lane & 15;
    const int kg    = lane >> 4;
    const int rgw   = wid >> 2;              // rowgroup 0/1
    const int ksub  = wid & 3;               // k sub-slice (32 wide)

    const int rb     = blockIdx.x & (RB - 1);
    const int chunk  = blockIdx.x >> 8;
    const int r0     = rb * 32;
    const int k0     = chunk * kchunk;
    const int nsteps = kchunk >> 7;

    // staging pointers: Vt 4 instrs/wave (4 rows each), A 2 instrs/wave (2 rows each)
    const short* vsrc[4]; short* vdst[4];
#pragma unroll
    for (int i = 0; i < 4; i++) {
        const int vrow = wid * 16 + i * 4 + (lane >> 4);
        vsrc[i] = Vt + (size_t)vrow * N_NODES + k0 + (size_t)(((lane & 15) ^ (vrow & 7)) * 8);
        vdst[i] = vt_s + (wid * 16 + i * 4) * KSTEP;
    }
    const float* asrc[2]; float* adst[2];
#pragma unroll
    for (int j = 0; j < 2; j++) {
        const int arow = wid * 4 + j * 2 + (lane >> 5);
        asrc[j] = A + (size_t)(r0 + arow) * N_NODES + k0 + (size_t)(((lane & 31) ^ (arow & 7)) * 4);
        adst[j] = a_s + (wid * 4 + j * 2) * KSTEP;
    }

    // LDS fragment read offsets (element units, swizzled: 16B chunk ^= row&7)
    const int a_row  = rgw * 16 + row_a;
    const int a_off0 = a_row * KSTEP + ((ksub * 32 + kg * 8 + 0) ^ ((a_row & 7) * 4));
    const int a_off1 = a_row * KSTEP + ((ksub * 32 + kg * 8 + 4) ^ ((a_row & 7) * 4));
    int v_off[8];
#pragma unroll
    for (int t = 0; t < 8; t++) {
        const int d = t * 16 + row_a;
        v_off[t] = d * KSTEP + ((ksub * 32 + kg * 8) ^ ((d & 7) * 8));
    }

    f32x4 acc[8];
#pragma unroll
    for (int t = 0; t < 8; t++) acc[t] = (f32x4)0.0f;
    float zacc = 0.0f;

    for (int ks = 0; ks < nsteps; ks++) {
        __syncthreads();                     // previous compute done; tiles free
#pragma unroll
        for (int i = 0; i < 4; i++) gload16(vsrc[i] + (size_t)ks * KSTEP, vdst[i]);
#pragma unroll
        for (int j = 0; j < 2; j++) gload16(asrc[j] + (size_t)ks * KSTEP, adst[j]);
        __syncthreads();                     // staged data visible (vmcnt drained)

        const f32x4 av0 = *(const f32x4*)(a_s + a_off0);
        const f32x4 av1 = *(const f32x4*)(a_s + a_off1);
        float p[8];
#pragma unroll
        for (int i = 0; i < 4; i++) {
            p[i]     = (av0[i] > MASK_THRESH) ? __expf(av0[i]) : 0.0f;
            p[i + 4] = (av1[i] > MASK_THRESH) ? __expf(av1[i]) : 0.0f;
        }
        bf16x8 af;
#pragma unroll
        for (int i = 0; i < 8; i++) { zacc += p[i]; af[i] = f2bf(p[i]); }
#pragma unroll
        for (int t = 0; t < 8; t++) {
            const bf16x8 bv = *(const bf16x8*)(vt_s + v_off[t]);
            acc[t] = __builtin_amdgcn_mfma_f32_16x16x32_bf16(af, bv, acc[t], 0, 0, 0);
        }
    }

    // ---- Z reduction: fold 4 kg groups; lanes 0..15 hold row partials ----
    zacc += __shfl_xor(zacc, 16);
    zacc += __shfl_xor(zacc, 32);
    __syncthreads();                         // all LDS reads of tiles done
    if (lane < 16) zs[wid][lane] = zacc;

    // ---- cross-wave accumulator reduction, one rowgroup at a time ----
    float* accs = (float*)smem;              // [4][16][132] = 33792 B
#pragma unroll
    for (int rg = 0; rg < 2; rg++) {
        if (rgw == rg) {
#pragma unroll
            for (int t = 0; t < 8; t++)
#pragma unroll
                for (int r = 0; r < 4; r++)
                    accs[(ksub * 16 + kg * 4 + r) * 132 + t * 16 + row_a] = acc[t][r];
        }
        __syncthreads();
        {
            const int row = tid >> 5;        // 0..15
            const int c4  = (tid & 31) * 4;  // 0..124
            float s0 = 0, s1 = 0, s2 = 0, s3 = 0, zt = 0;
#pragma unroll
            for (int w = 0; w < 4; w++) {
                const float* p = &accs[(w * 16 + row) * 132 + c4];
                s0 += p[0]; s1 += p[1]; s2 += p[2]; s3 += p[3];
                zt += zs[rg * 4 + w][row];
            }
            const int orow = r0 + rg * 16 + row;
            if (WRITE_PARTIAL) {
                f32x4 v = {s0, s1, s2, s3};
                *(f32x4*)(dst + ((size_t)chunk * N_NODES + orow) * DIM + c4) = v;
            } else {
                f32x4 v;
                v[0] = s0 / zt; v[1] = s1 / zt; v[2] = s2 / zt; v[3] = s3 / zt;
#pragma unroll
                for (int j = 0; j < 4; j++) v[j] = (v[j] > 0.0f) ? v[j] : 0.01f * v[j];
                *(f32x4*)(dst + (size_t)orow * DIM + c4) = v;
            }
        }
        __syncthreads();
    }
    if (WRITE_PARTIAL && tid < 32) {
        const int rg = tid >> 4, ra = tid & 15;
        float z = 0.0f;
#pragma unroll
        for (int w = 0; w < 4; w++) z += zs[rg * 4 + w][ra];
        Zp[(size_t)chunk * N_NODES + r0 + rg * 16 + ra] = z;
    }
}

// ---------------------------------------------------------------------------
// Kernel 3: sum S partials, normalize, leaky_relu. float4 per thread.
// ---------------------------------------------------------------------------
__global__ __launch_bounds__(256) void reduce_kernel(
    const float* __restrict__ num, const float* __restrict__ Zp,
    float* __restrict__ out, int S) {
    const size_t i4 = (size_t)blockIdx.x * 256 + threadIdx.x;  // quad index
    const int r  = (int)(i4 >> 5);
    const int c4 = (int)(i4 & 31) * 4;
    f32x4 s = (f32x4)0.0f;
    float z = 0.0f;
    for (int p = 0; p < S; p++) {
        const f32x4 v = *(const f32x4*)(num + ((size_t)p * N_NODES + r) * DIM + c4);
        s += v;
        z += Zp[(size_t)p * N_NODES + r];
    }
    f32x4 o;
#pragma unroll
    for (int j = 0; j < 4; j++) {
        const float v = s[j] / z;
        o[j] = (v > 0.0f) ? v : 0.01f * v;
    }
    *(f32x4*)(out + (size_t)r * DIM + c4) = o;
}

extern "C" void kernel_launch(void* const* d_in, const int* in_sizes, int n_in,
                              void* d_out, int out_size, void* d_ws, size_t ws_size,
                              hipStream_t stream) {
    const float* A = (const float*)d_in[0];
    const float* X = (const float*)d_in[1];
    const float* W = (const float*)d_in[2];
    const float* b = (const float*)d_in[3];
    float* out = (float*)d_out;

    const size_t VT_BYTES = (size_t)DIM * N_NODES * 2;   // 2 MiB
    short* Vt = (short*)d_ws;
    build_vt_kernel<<<N_NODES / 32, 256, 0, stream>>>(X, W, b, Vt);

    const size_t per_split = ((size_t)N_NODES * DIM + N_NODES) * sizeof(float);
    int S = 1;
    for (int cand = 4; cand >= 1; cand >>= 1) {
        if (VT_BYTES + (size_t)cand * per_split <= ws_size) { S = cand; break; }
    }

    if (S >= 2) {
        float* num = (float*)((char*)d_ws + VT_BYTES);
        float* Zp  = num + (size_t)S * N_NODES * DIM;
        fused_kernel<1><<<RB * S, 512, 0, stream>>>(A, Vt, num, Zp, N_NODES / S);
        reduce_kernel<<<(N_NODES * DIM / 4) / 256, 256, 0, stream>>>(num, Zp, out, S);
    } else {
        fused_kernel<0><<<RB, 512, 0, stream>>>(A, Vt, out, nullptr, N_NODES);
    }
}